// Round 11
// baseline (83.249 us; speedup 1.0000x reference)
//
#include <hip/hip_runtime.h>

// Bidirectional chamfer, B=4, N=M=5000, D=3, fp32.
// R11 = R10 (fused staging, wave-pair j-split, QW=10 query rows in SGPRs)
// with two refinements:
//  - Overlap split: jh=0 covers float4 [0,640), jh=1 covers [610,1250) —
//    both exactly 10 UNMASKED iterations (30-f4 overlap is harmless for min).
//  - No reduce kernel: blocks atomicAdd their pre-scaled sums into out[0]
//    (zeroed by a 4-byte hipMemsetAsync; 504 same-address float atomics).

#define BB      4
#define NP      5000
#define THREADS 1024
#define WAVES   16
#define PAIRS   8                  // wave pairs per block
#define QW      10                 // query rows per pair (SGPR-resident)
#define QPB     (PAIRS * QW)       // 80 rows per block
#define XBLKS   63                 // 63*80 = 5040 >= 5000 (tail rows masked)
#define NF4     (NP / 4)           // 1250 float4 per SoA array
#define EB1     610                // jh=1 base: [610,1250) = 640 f4 = 10 iters
#define BIGF    3.0e38f

__global__ __launch_bounds__(THREADS) void dl_chamfer_kernel(
    const float* __restrict__ pred, const float* __restrict__ gt,
    float* __restrict__ out) {
    const int qblk = blockIdx.x;            // 0..62
    const int bz   = blockIdx.y;            // 0..7
    const int b    = bz >> 1;
    const int dir  = bz & 1;
    const float* qsrc = dir ? gt   : pred;
    const float* tsrc = dir ? pred : gt;

    const int lane = threadIdx.x & 63;
    const int wave = __builtin_amdgcn_readfirstlane(threadIdx.x >> 6);
    const int pair = wave >> 1;
    const int jh   = wave & 1;

    // LDS: X[NP] | Y[NP] | Z[NP] | W[NP] | mshare[16*QW] | wsum[PAIRS]
    __shared__ float smem[4 * NP + WAVES * QW + PAIRS];
    float* mshare = smem + 4 * NP;
    float* wsum   = smem + 4 * NP + WAVES * QW;

    // ---- stage raw target float3 (coalesced dwordx4), scatter to SoA LDS
    const float4* tb4 = (const float4*)(tsrc + (size_t)b * NP * 3); // 3750 f4
    for (int f = threadIdx.x; f < (3 * NP) / 4; f += THREADS) {
        const float4 v = tb4[f];
        const float vv[4] = {v.x, v.y, v.z, v.w};
        const int i0 = 4 * f;
        #pragma unroll
        for (int c = 0; c < 4; ++c) {
            const int i = i0 + c;
            const int j = i / 3;            // magic-mul div
            smem[(i - 3 * j) * NP + j] = vv[c];
        }
    }

    // ---- this pair's 10 query rows (wave-uniform -> SGPRs)
    float qx[QW], qy[QW], qz[QW], m[QW];
    const int qbase = qblk * QPB + pair * QW;
    const float* qb = qsrc + (size_t)b * NP * 3;
    #pragma unroll
    for (int r = 0; r < QW; ++r) {
        const int qi = (qbase + r < NP) ? (qbase + r) : 0;
        qx[r] = -2.0f * qb[3 * qi];
        qy[r] = -2.0f * qb[3 * qi + 1];
        qz[r] = -2.0f * qb[3 * qi + 2];
        m[r]  = BIGF;
    }
    __syncthreads();

    // ---- norm pass: W[j] = |g_j|^2 (conflict-free strided b32)
    for (int j = threadIdx.x; j < NP; j += THREADS) {
        const float x = smem[j], y = smem[NP + j], z = smem[2 * NP + j];
        smem[3 * NP + j] = x * x + y * y + z * z;
    }
    __syncthreads();

    // ---- barrier-free main loop: 10 UNMASKED iterations per wave.
    // jh=0: f4 [0,640); jh=1: f4 [610,1250). Overlap double-counts 120
    // targets in the min — idempotent, so correct.
    const float4* X4 = (const float4*)smem;
    const float4* Y4 = X4 + NF4;
    const float4* Z4 = X4 + 2 * NF4;
    const float4* W4 = X4 + 3 * NF4;
    const int ebase = (jh ? EB1 : 0) + lane;
    #pragma unroll 2
    for (int k = 0; k < 10; ++k) {
        const int e = ebase + k * 64;
        const float4 xv = X4[e], yv = Y4[e], zv = Z4[e], wv = W4[e];
        const float xs[4] = {xv.x, xv.y, xv.z, xv.w};
        const float ys[4] = {yv.x, yv.y, yv.z, yv.w};
        const float zs[4] = {zv.x, zv.y, zv.z, zv.w};
        const float ws[4] = {wv.x, wv.y, wv.z, wv.w};
        #pragma unroll
        for (int c = 0; c < 4; ++c) {
            #pragma unroll
            for (int r = 0; r < QW; ++r) {
                // |g|^2 - 2 q.g : 3 fma + min per pair
                float d = __builtin_fmaf(qz[r], zs[c], ws[c]);
                d = __builtin_fmaf(qy[r], ys[c], d);
                d = __builtin_fmaf(qx[r], xs[c], d);
                m[r] = fminf(m[r], d);
            }
        }
    }

    // ---- cross-lane min butterfly (lanes covered disjoint targets)
    #pragma unroll
    for (int r = 0; r < QW; ++r) {
        float v = m[r];
        #pragma unroll
        for (int off = 1; off < 64; off <<= 1)
            v = fminf(v, __shfl_xor(v, off, 64));
        m[r] = v;
    }

    // ---- cross-wave (pair) combine + row sums
    if (lane == 0) {
        #pragma unroll
        for (int r = 0; r < QW; ++r) mshare[wave * QW + r] = m[r];
    }
    __syncthreads();
    if (jh == 0 && lane == 0) {
        float s = 0.0f;
        #pragma unroll
        for (int r = 0; r < QW; ++r) {
            const float q2 = 0.25f * (qx[r] * qx[r] + qy[r] * qy[r] +
                                      qz[r] * qz[r]);
            const float mm = fminf(m[r], mshare[(wave + 1) * QW + r]);
            const float c  = fmaxf(q2 + mm, 0.0f);
            s += (qbase + r < NP) ? c : 0.0f;
        }
        wsum[pair] = s;
    }
    __syncthreads();
    if (threadIdx.x == 0) {
        float s = 0.0f;
        #pragma unroll
        for (int p = 0; p < PAIRS; ++p) s += wsum[p];
        atomicAdd(out, s * (1.0f / (float)(BB * NP)));  // device-scope
    }
}

extern "C" void kernel_launch(void* const* d_in, const int* in_sizes, int n_in,
                              void* d_out, int out_size, void* d_ws, size_t ws_size,
                              hipStream_t stream) {
    const float* pred = (const float*)d_in[0];
    const float* gt   = (const float*)d_in[1];
    float* out        = (float*)d_out;

    hipMemsetAsync(out, 0, sizeof(float), stream);   // graph-legal, 4 B
    dl_chamfer_kernel<<<dim3(XBLKS, 2 * BB), THREADS, 0, stream>>>(
        pred, gt, out);
}